// Round 1
// baseline (3414.495 us; speedup 1.0000x reference)
//
#include <hip/hip_runtime.h>
#include <hip/hip_bf16.h>

// GaussianMMD: out = mean(Kxx) + mean(Kyy) - 2*mean(Kxy), K = exp(-||a-b||^2/2048)
// N=8192, D=1024, fp32 in, fp32 scalar out.
// Strategy: z = [x;y] (16384 rows), weight w=+1 for x, -1 for y.
//   S = sum_{i,j in 2N} w_i w_j exp(-||zi-zj||^2/sigma);  out = S / N^2.
// Symmetric => compute only tile-pairs ti<=tj (factor 2 off-diagonal).
// fp32 vector-FMA tiled GEMM-like kernel (no fp32 MFMA on CDNA4).

#define N_ROWS 8192
#define DIM 1024
#define TWO_N 16384
#define TILE 128
#define BK 32
#define NTILES 128                 // TWO_N / TILE
#define NBLOCKS (NTILES * (NTILES + 1) / 2)   // 8256
#define INV_SIGMA (1.0f / 2048.0f)

__global__ __launch_bounds__(256) void mmd_norms(const float* __restrict__ x,
                                                 const float* __restrict__ y,
                                                 float* __restrict__ zn) {
    int row = blockIdx.x * 4 + (threadIdx.x >> 6);
    int lane = threadIdx.x & 63;
    const float* p = (row < N_ROWS) ? (x + (size_t)row * DIM)
                                    : (y + (size_t)(row - N_ROWS) * DIM);
    float s = 0.0f;
#pragma unroll
    for (int c = 0; c < 4; ++c) {
        float4 v = *(const float4*)(p + (size_t)(lane + c * 64) * 4);
        s = fmaf(v.x, v.x, s);
        s = fmaf(v.y, v.y, s);
        s = fmaf(v.z, v.z, s);
        s = fmaf(v.w, v.w, s);
    }
#pragma unroll
    for (int o = 32; o > 0; o >>= 1) s += __shfl_down(s, o);
    if (lane == 0) zn[row] = s;
}

__global__ __launch_bounds__(256) void mmd_main(const float* __restrict__ x,
                                                const float* __restrict__ y,
                                                const float* __restrict__ zn,
                                                double* __restrict__ partials) {
    int bid = blockIdx.x;
    // triangle decode: bid -> (ti, tj) with ti <= tj
    int tj = (int)((sqrtf(8.0f * (float)bid + 1.0f) - 1.0f) * 0.5f);
    while ((tj + 1) * (tj + 2) / 2 <= bid) ++tj;
    while (tj * (tj + 1) / 2 > bid) --tj;
    int ti = bid - tj * (tj + 1) / 2;

    const int xtiles = N_ROWS / TILE;  // 64
    const float* A = (ti < xtiles) ? (x + (size_t)ti * TILE * DIM)
                                   : (y + (size_t)(ti - xtiles) * TILE * DIM);
    const float* B = (tj < xtiles) ? (x + (size_t)tj * TILE * DIM)
                                   : (y + (size_t)(tj - xtiles) * TILE * DIM);
    float w = ((ti < xtiles) == (tj < xtiles)) ? 1.0f : -1.0f;
    float factor = (ti == tj) ? w : 2.0f * w;

    __shared__ float sa[BK][TILE];
    __shared__ float sb[BK][TILE];
    __shared__ double red[256];

    int tid = threadIdx.x;
    int tx = tid & 15;
    int ty = tid >> 4;

    float acc[8][8];
#pragma unroll
    for (int r = 0; r < 8; ++r)
#pragma unroll
        for (int s = 0; s < 8; ++s) acc[r][s] = 0.0f;

    for (int k0 = 0; k0 < DIM; k0 += BK) {
#pragma unroll
        for (int u = 0; u < 4; ++u) {
            int f = tid + u * 256;      // 0..1023 float4 slots per tile
            int row = f >> 3;           // 8 float4 per row-chunk of BK=32
            int kk = (f & 7) << 2;
            float4 va = *(const float4*)(A + (size_t)row * DIM + k0 + kk);
            float4 vb = *(const float4*)(B + (size_t)row * DIM + k0 + kk);
            sa[kk + 0][row] = va.x; sa[kk + 1][row] = va.y;
            sa[kk + 2][row] = va.z; sa[kk + 3][row] = va.w;
            sb[kk + 0][row] = vb.x; sb[kk + 1][row] = vb.y;
            sb[kk + 2][row] = vb.z; sb[kk + 3][row] = vb.w;
        }
        __syncthreads();
#pragma unroll 8
        for (int k = 0; k < BK; ++k) {
            float4 a0 = *(const float4*)&sa[k][ty * 8];
            float4 a1 = *(const float4*)&sa[k][ty * 8 + 4];
            float4 b0 = *(const float4*)&sb[k][tx * 8];
            float4 b1 = *(const float4*)&sb[k][tx * 8 + 4];
            float af[8] = {a0.x, a0.y, a0.z, a0.w, a1.x, a1.y, a1.z, a1.w};
            float bf[8] = {b0.x, b0.y, b0.z, b0.w, b1.x, b1.y, b1.z, b1.w};
#pragma unroll
            for (int r = 0; r < 8; ++r)
#pragma unroll
                for (int s = 0; s < 8; ++s)
                    acc[r][s] = fmaf(af[r], bf[s], acc[r][s]);
        }
        __syncthreads();
    }

    // epilogue: kernel values + local sum
    float xnrm[8], ynrm[8];
#pragma unroll
    for (int r = 0; r < 8; ++r) xnrm[r] = zn[ti * TILE + ty * 8 + r];
#pragma unroll
    for (int s = 0; s < 8; ++s) ynrm[s] = zn[tj * TILE + tx * 8 + s];

    float lsum = 0.0f;
#pragma unroll
    for (int r = 0; r < 8; ++r)
#pragma unroll
        for (int s = 0; s < 8; ++s) {
            float d2 = fmaf(-2.0f, acc[r][s], xnrm[r] + ynrm[s]);
            lsum += __expf(-d2 * INV_SIGMA);
        }

    red[tid] = (double)lsum;
    __syncthreads();
#pragma unroll
    for (int ofs = 128; ofs > 0; ofs >>= 1) {
        if (tid < ofs) red[tid] += red[tid + ofs];
        __syncthreads();
    }
    if (tid == 0) partials[bid] = red[0] * (double)factor;
}

__global__ __launch_bounds__(256) void mmd_reduce(const double* __restrict__ partials,
                                                  float* __restrict__ out, int n) {
    __shared__ double red[256];
    double s = 0.0;
    for (int i = threadIdx.x; i < n; i += 256) s += partials[i];
    red[threadIdx.x] = s;
    __syncthreads();
    for (int ofs = 128; ofs > 0; ofs >>= 1) {
        if (threadIdx.x < ofs) red[threadIdx.x] += red[threadIdx.x + ofs];
        __syncthreads();
    }
    if (threadIdx.x == 0)
        out[0] = (float)(red[0] / ((double)N_ROWS * (double)N_ROWS));
}

extern "C" void kernel_launch(void* const* d_in, const int* in_sizes, int n_in,
                              void* d_out, int out_size, void* d_ws, size_t ws_size,
                              hipStream_t stream) {
    const float* x = (const float*)d_in[0];
    const float* y = (const float*)d_in[1];
    float* out = (float*)d_out;

    float* zn = (float*)d_ws;                                   // 16384 f32 = 64 KiB
    double* partials = (double*)((char*)d_ws + 16384 * sizeof(float)); // 8256 f64

    mmd_norms<<<TWO_N / 4, 256, 0, stream>>>(x, y, zn);
    mmd_main<<<NBLOCKS, 256, 0, stream>>>(x, y, zn, partials);
    mmd_reduce<<<1, 256, 0, stream>>>(partials, out, NBLOCKS);
}

// Round 2
// 368.476 us; speedup vs baseline: 9.2665x; 9.2665x over previous
//
#include <hip/hip_runtime.h>
#include <hip/hip_bf16.h>

// GaussianMMD: out = mean(Kxx) + mean(Kyy) - 2*mean(Kxy), K = exp(-||a-b||^2/2048)
// N=8192, D=1024, fp32 in, fp32 scalar out.
// R2: bf16 MFMA path. z=[x;y] rounded to bf16 (zh in ws); norms computed FROM zh
// so result = exact MMD of perturbed points (bias cancels in +1+1-2 combo).
// Triangle tile-pairs ti<=tj, 128x128 tiles, m97-style global_load_lds staging.

#define N_ROWS 8192
#define DIM 1024
#define TWO_N 16384
#define TILE 128
#define BK 32
#define NTILES 128
#define NBLOCKS (NTILES * (NTILES + 1) / 2)   // 8256
#define INV_SIGMA (1.0f / 2048.0f)

typedef short s16x8 __attribute__((ext_vector_type(8)));
typedef float f32x4 __attribute__((ext_vector_type(4)));

typedef __attribute__((address_space(3))) unsigned int lds_u32_t;
typedef const __attribute__((address_space(1))) unsigned int glb_u32_t;

__device__ __forceinline__ void gload16(const void* g, void* l) {
    __builtin_amdgcn_global_load_lds((glb_u32_t*)g, (lds_u32_t*)l, 16, 0, 0);
}

__device__ __forceinline__ unsigned short f2bf_rne(float f, float* back) {
    unsigned int u = __float_as_uint(f);
    unsigned int r = (u + 0x7fffu + ((u >> 16) & 1u)) >> 16;
    *back = __uint_as_float(r << 16);
    return (unsigned short)r;
}

// ---- fast path kernels (bf16 MFMA) ----

__global__ __launch_bounds__(256) void mmd_convert(const float* __restrict__ x,
                                                   const float* __restrict__ y,
                                                   unsigned short* __restrict__ zh,
                                                   float* __restrict__ zn) {
    int row = blockIdx.x * 4 + (threadIdx.x >> 6);
    int lane = threadIdx.x & 63;
    const float* p = (row < N_ROWS) ? (x + (size_t)row * DIM)
                                    : (y + (size_t)(row - N_ROWS) * DIM);
    unsigned short* q = zh + (size_t)row * DIM;
    float s = 0.0f;
#pragma unroll
    for (int c = 0; c < 4; ++c) {
        int idx = (lane + c * 64) * 4;
        float4 v = *(const float4*)(p + idx);
        float b0, b1, b2, b3;
        ushort4 o;
        o.x = f2bf_rne(v.x, &b0);
        o.y = f2bf_rne(v.y, &b1);
        o.z = f2bf_rne(v.z, &b2);
        o.w = f2bf_rne(v.w, &b3);
        s = fmaf(b0, b0, s);
        s = fmaf(b1, b1, s);
        s = fmaf(b2, b2, s);
        s = fmaf(b3, b3, s);
        *(ushort4*)(q + idx) = o;
    }
#pragma unroll
    for (int o = 32; o > 0; o >>= 1) s += __shfl_down(s, o);
    if (lane == 0) zn[row] = s;
}

__global__ __launch_bounds__(256) void mmd_main_bf16(const unsigned short* __restrict__ zh,
                                                     const float* __restrict__ zn,
                                                     double* __restrict__ partials) {
    __shared__ __align__(16) short sa[TILE][BK];
    __shared__ __align__(16) short sb[TILE][BK];
    __shared__ double red[256];

    int bid = blockIdx.x;
    int tid = threadIdx.x;

    // triangle decode: bid -> (ti, tj), ti <= tj
    int tj = (int)((sqrtf(8.0f * (float)bid + 1.0f) - 1.0f) * 0.5f);
    while ((tj + 1) * (tj + 2) / 2 <= bid) ++tj;
    while (tj * (tj + 1) / 2 > bid) --tj;
    int ti = bid - tj * (tj + 1) / 2;

    const int rowA = ti * TILE;
    const int rowB = tj * TILE;
    float w = ((ti < 64) == (tj < 64)) ? 1.0f : -1.0f;
    float factor = (ti == tj) ? w : 2.0f * w;

    const int l = tid & 63;
    const int wv = tid >> 6;
    const int wr = (wv >> 1) * 64;   // wave row offset in tile
    const int wc = (wv & 1) * 64;    // wave col offset in tile
    const int fr = l & 15;           // fragment row/col index
    const int fg = l >> 4;           // k-group

    f32x4 acc[4][4];
#pragma unroll
    for (int g = 0; g < 4; ++g)
#pragma unroll
        for (int h = 0; h < 4; ++h) acc[g][h] = (f32x4){0.f, 0.f, 0.f, 0.f};

    const int srow = tid >> 2;          // 0..63
    const int skl = (tid & 3) << 3;     // 0,8,16,24

    for (int k0 = 0; k0 < DIM; k0 += BK) {
        __syncthreads();
        const unsigned short* gA = zh + (size_t)(rowA + srow) * DIM + k0 + skl;
        const unsigned short* gB = zh + (size_t)(rowB + srow) * DIM + k0 + skl;
        gload16(gA, (char*)&sa[0][0] + tid * 16);
        gload16(gA + 64 * DIM, (char*)&sa[64][0] + tid * 16);
        gload16(gB, (char*)&sb[0][0] + tid * 16);
        gload16(gB + 64 * DIM, (char*)&sb[64][0] + tid * 16);
        __syncthreads();

        s16x8 af[4], bf[4];
#pragma unroll
        for (int g = 0; g < 4; ++g) {
            af[g] = *(const s16x8*)&sa[wr + g * 16 + fr][fg * 8];
            bf[g] = *(const s16x8*)&sb[wc + g * 16 + fr][fg * 8];
        }
#pragma unroll
        for (int g = 0; g < 4; ++g)
#pragma unroll
            for (int h = 0; h < 4; ++h)
                acc[g][h] = __builtin_amdgcn_mfma_f32_16x16x32_bf16(af[g], bf[h], acc[g][h], 0, 0, 0);
    }

    // epilogue: d2 = |a|^2 + |b|^2 - 2 a.b ; accumulate exp
    float rn[16];
#pragma unroll
    for (int g = 0; g < 4; ++g)
#pragma unroll
        for (int v = 0; v < 4; ++v)
            rn[g * 4 + v] = zn[rowA + wr + g * 16 + fg * 4 + v];
    float cn[4];
#pragma unroll
    for (int h = 0; h < 4; ++h) cn[h] = zn[rowB + wc + h * 16 + fr];

    float lsum = 0.0f;
#pragma unroll
    for (int g = 0; g < 4; ++g)
#pragma unroll
        for (int h = 0; h < 4; ++h)
#pragma unroll
            for (int v = 0; v < 4; ++v) {
                float d2 = fmaf(-2.0f, acc[g][h][v], rn[g * 4 + v] + cn[h]);
                lsum += __expf(-d2 * INV_SIGMA);
            }

    red[tid] = (double)lsum;
    __syncthreads();
#pragma unroll
    for (int ofs = 128; ofs > 0; ofs >>= 1) {
        if (tid < ofs) red[tid] += red[tid + ofs];
        __syncthreads();
    }
    if (tid == 0) partials[bid] = red[0] * (double)factor;
}

__global__ __launch_bounds__(256) void mmd_reduce(const double* __restrict__ partials,
                                                  float* __restrict__ out, int n) {
    __shared__ double red[256];
    double s = 0.0;
    for (int i = threadIdx.x; i < n; i += 256) s += partials[i];
    red[threadIdx.x] = s;
    __syncthreads();
    for (int ofs = 128; ofs > 0; ofs >>= 1) {
        if (threadIdx.x < ofs) red[threadIdx.x] += red[threadIdx.x + ofs];
        __syncthreads();
    }
    if (threadIdx.x == 0)
        out[0] = (float)(red[0] / ((double)N_ROWS * (double)N_ROWS));
}

// ---- fallback fp32 path (R1, proven) ----

__global__ __launch_bounds__(256) void mmd_norms_f32(const float* __restrict__ x,
                                                     const float* __restrict__ y,
                                                     float* __restrict__ zn) {
    int row = blockIdx.x * 4 + (threadIdx.x >> 6);
    int lane = threadIdx.x & 63;
    const float* p = (row < N_ROWS) ? (x + (size_t)row * DIM)
                                    : (y + (size_t)(row - N_ROWS) * DIM);
    float s = 0.0f;
#pragma unroll
    for (int c = 0; c < 4; ++c) {
        float4 v = *(const float4*)(p + (size_t)(lane + c * 64) * 4);
        s = fmaf(v.x, v.x, s);
        s = fmaf(v.y, v.y, s);
        s = fmaf(v.z, v.z, s);
        s = fmaf(v.w, v.w, s);
    }
#pragma unroll
    for (int o = 32; o > 0; o >>= 1) s += __shfl_down(s, o);
    if (lane == 0) zn[row] = s;
}

__global__ __launch_bounds__(256) void mmd_main_f32(const float* __restrict__ x,
                                                    const float* __restrict__ y,
                                                    const float* __restrict__ zn,
                                                    double* __restrict__ partials) {
    int bid = blockIdx.x;
    int tj = (int)((sqrtf(8.0f * (float)bid + 1.0f) - 1.0f) * 0.5f);
    while ((tj + 1) * (tj + 2) / 2 <= bid) ++tj;
    while (tj * (tj + 1) / 2 > bid) --tj;
    int ti = bid - tj * (tj + 1) / 2;

    const int xtiles = N_ROWS / TILE;
    const float* A = (ti < xtiles) ? (x + (size_t)ti * TILE * DIM)
                                   : (y + (size_t)(ti - xtiles) * TILE * DIM);
    const float* B = (tj < xtiles) ? (x + (size_t)tj * TILE * DIM)
                                   : (y + (size_t)(tj - xtiles) * TILE * DIM);
    float w = ((ti < xtiles) == (tj < xtiles)) ? 1.0f : -1.0f;
    float factor = (ti == tj) ? w : 2.0f * w;

    __shared__ float fsa[BK][TILE];
    __shared__ float fsb[BK][TILE];
    __shared__ double red[256];

    int tid = threadIdx.x;
    int tx = tid & 15;
    int ty = tid >> 4;

    float acc[8][8];
#pragma unroll
    for (int r = 0; r < 8; ++r)
#pragma unroll
        for (int s = 0; s < 8; ++s) acc[r][s] = 0.0f;

    for (int k0 = 0; k0 < DIM; k0 += BK) {
#pragma unroll
        for (int u = 0; u < 4; ++u) {
            int f = tid + u * 256;
            int row = f >> 3;
            int kk = (f & 7) << 2;
            float4 va = *(const float4*)(A + (size_t)row * DIM + k0 + kk);
            float4 vb = *(const float4*)(B + (size_t)row * DIM + k0 + kk);
            fsa[kk + 0][row] = va.x; fsa[kk + 1][row] = va.y;
            fsa[kk + 2][row] = va.z; fsa[kk + 3][row] = va.w;
            fsb[kk + 0][row] = vb.x; fsb[kk + 1][row] = vb.y;
            fsb[kk + 2][row] = vb.z; fsb[kk + 3][row] = vb.w;
        }
        __syncthreads();
#pragma unroll 8
        for (int k = 0; k < BK; ++k) {
            float4 a0 = *(const float4*)&fsa[k][ty * 8];
            float4 a1 = *(const float4*)&fsa[k][ty * 8 + 4];
            float4 b0 = *(const float4*)&fsb[k][tx * 8];
            float4 b1 = *(const float4*)&fsb[k][tx * 8 + 4];
            float af[8] = {a0.x, a0.y, a0.z, a0.w, a1.x, a1.y, a1.z, a1.w};
            float bfv[8] = {b0.x, b0.y, b0.z, b0.w, b1.x, b1.y, b1.z, b1.w};
#pragma unroll
            for (int r = 0; r < 8; ++r)
#pragma unroll
                for (int s = 0; s < 8; ++s)
                    acc[r][s] = fmaf(af[r], bfv[s], acc[r][s]);
        }
        __syncthreads();
    }

    float xnrm[8], ynrm[8];
#pragma unroll
    for (int r = 0; r < 8; ++r) xnrm[r] = zn[ti * TILE + ty * 8 + r];
#pragma unroll
    for (int s = 0; s < 8; ++s) ynrm[s] = zn[tj * TILE + tx * 8 + s];

    float lsum = 0.0f;
#pragma unroll
    for (int r = 0; r < 8; ++r)
#pragma unroll
        for (int s = 0; s < 8; ++s) {
            float d2 = fmaf(-2.0f, acc[r][s], xnrm[r] + ynrm[s]);
            lsum += __expf(-d2 * INV_SIGMA);
        }

    red[tid] = (double)lsum;
    __syncthreads();
#pragma unroll
    for (int ofs = 128; ofs > 0; ofs >>= 1) {
        if (tid < ofs) red[tid] += red[tid + ofs];
        __syncthreads();
    }
    if (tid == 0) partials[bid] = red[0] * (double)factor;
}

extern "C" void kernel_launch(void* const* d_in, const int* in_sizes, int n_in,
                              void* d_out, int out_size, void* d_ws, size_t ws_size,
                              hipStream_t stream) {
    const float* x = (const float*)d_in[0];
    const float* y = (const float*)d_in[1];
    float* out = (float*)d_out;

    const size_t zh_bytes = (size_t)TWO_N * DIM * sizeof(unsigned short); // 32 MiB
    const size_t zn_bytes = (size_t)TWO_N * sizeof(float);                // 64 KiB
    const size_t pt_bytes = (size_t)NBLOCKS * sizeof(double);             // 66 KiB
    const size_t need = zh_bytes + zn_bytes + pt_bytes;

    if (ws_size >= need) {
        unsigned short* zh = (unsigned short*)d_ws;
        float* zn = (float*)((char*)d_ws + zh_bytes);
        double* partials = (double*)((char*)d_ws + zh_bytes + zn_bytes);
        mmd_convert<<<TWO_N / 4, 256, 0, stream>>>(x, y, zh, zn);
        mmd_main_bf16<<<NBLOCKS, 256, 0, stream>>>(zh, zn, partials);
        mmd_reduce<<<1, 256, 0, stream>>>(partials, out, NBLOCKS);
    } else {
        float* zn = (float*)d_ws;
        double* partials = (double*)((char*)d_ws + (size_t)TWO_N * sizeof(float));
        mmd_norms_f32<<<TWO_N / 4, 256, 0, stream>>>(x, y, zn);
        mmd_main_f32<<<NBLOCKS, 256, 0, stream>>>(x, y, zn, partials);
        mmd_reduce<<<1, 256, 0, stream>>>(partials, out, NBLOCKS);
    }
}

// Round 3
// 302.146 us; speedup vs baseline: 11.3008x; 1.2195x over previous
//
#include <hip/hip_runtime.h>
#include <hip/hip_bf16.h>

// GaussianMMD: out = mean(Kxx)+mean(Kyy)-2*mean(Kxy), K=exp(-||a-b||^2/2048)
// N=8192, D=1024 fp32 in, fp32 scalar out.
// R3: 256x256-tile 8-phase pipelined bf16 MFMA kernel (T2 swizzle + T3/T4
// counted vmcnt + T5 setprio), z=[x;y] bf16 in ws, norms from bf16 data.

#define N_ROWS 8192
#define DIM 1024
#define TWO_N 16384
#define BT 256
#define BK 64
#define NT2 64                      // TWO_N / BT
#define NBLK2 (NT2 * (NT2 + 1) / 2) // 2080
#define NKT (DIM / BK)              // 16
#define INV_SIGMA (1.0f / 2048.0f)

typedef short s16x8 __attribute__((ext_vector_type(8)));
typedef float f32x4 __attribute__((ext_vector_type(4)));

typedef __attribute__((address_space(3))) unsigned int lds_u32_t;
typedef const __attribute__((address_space(1))) unsigned int glb_u32_t;

__device__ __forceinline__ void gload16(const void* g, void* l) {
    __builtin_amdgcn_global_load_lds((glb_u32_t*)g, (lds_u32_t*)l, 16, 0, 0);
}

__device__ __forceinline__ unsigned short f2bf_rne(float f, float* back) {
    unsigned int u = __float_as_uint(f);
    unsigned int r = (u + 0x7fffu + ((u >> 16) & 1u)) >> 16;
    *back = __uint_as_float(r << 16);
    return (unsigned short)r;
}

#define SBAR() do { __builtin_amdgcn_sched_barrier(0); \
                    __builtin_amdgcn_s_barrier();      \
                    __builtin_amdgcn_sched_barrier(0); } while (0)

// ---- convert fp32 -> bf16, norms from bf16 ----
__global__ __launch_bounds__(256) void mmd_convert(const float* __restrict__ x,
                                                   const float* __restrict__ y,
                                                   unsigned short* __restrict__ zh,
                                                   float* __restrict__ zn) {
    int row = blockIdx.x * 4 + (threadIdx.x >> 6);
    int lane = threadIdx.x & 63;
    const float* p = (row < N_ROWS) ? (x + (size_t)row * DIM)
                                    : (y + (size_t)(row - N_ROWS) * DIM);
    unsigned short* q = zh + (size_t)row * DIM;
    float s = 0.0f;
#pragma unroll
    for (int c = 0; c < 4; ++c) {
        int idx = (lane + c * 64) * 4;
        float4 v = *(const float4*)(p + idx);
        float b0, b1, b2, b3;
        ushort4 o;
        o.x = f2bf_rne(v.x, &b0);
        o.y = f2bf_rne(v.y, &b1);
        o.z = f2bf_rne(v.z, &b2);
        o.w = f2bf_rne(v.w, &b3);
        s = fmaf(b0, b0, s);
        s = fmaf(b1, b1, s);
        s = fmaf(b2, b2, s);
        s = fmaf(b3, b3, s);
        *(ushort4*)(q + idx) = o;
    }
#pragma unroll
    for (int o = 32; o > 0; o >>= 1) s += __shfl_down(s, o);
    if (lane == 0) zn[row] = s;
}

// ---- main: 256x256 tile, 8 waves, 8-phase-per-2-Ktiles pipeline ----
__global__ __launch_bounds__(512, 2) void mmd_main8(const unsigned short* __restrict__ zh,
                                                    const float* __restrict__ zn,
                                                    double* __restrict__ partials) {
    __shared__ __align__(16) short lsA[2][BT * BK];  // 64 KiB
    __shared__ __align__(16) short lsB[2][BT * BK];  // 64 KiB
    __shared__ double red[8];

    const int tid = threadIdx.x;
    const int bid0 = blockIdx.x;
    const int bid = (bid0 & 7) * (NBLK2 / 8) + (bid0 >> 3);  // XCD swizzle (2080%8==0)

    int tj = (int)((sqrtf(8.0f * (float)bid + 1.0f) - 1.0f) * 0.5f);
    while ((tj + 1) * (tj + 2) / 2 <= bid) ++tj;
    while (tj * (tj + 1) / 2 > bid) --tj;
    const int ti = bid - tj * (tj + 1) / 2;

    const int rA = ti * BT, rB = tj * BT;
    const float w = ((ti < 32) == (tj < 32)) ? 1.0f : -1.0f;
    const float factor = (ti == tj) ? w : 2.0f * w;

    const int l = tid & 63;
    const int wid = tid >> 6;
    const int wr = wid >> 2;  // 0..1
    const int wc = wid & 3;   // 0..3
    const int fr = l & 15;
    const int fg = l >> 4;

    // staging addresses (pre-swizzled global source, linear LDS dest)
    const int rowoff = tid >> 3;                          // 0..63
    const int kswz = ((tid & 7) ^ (rowoff & 7)) << 3;     // 0..56 (bf16 elems)
    const unsigned short* pA = zh + (size_t)(rA + rowoff) * DIM + kswz;
    const unsigned short* pB = zh + (size_t)(rB + rowoff) * DIM + kswz;
    short* lA = &lsA[0][0];
    short* lB = &lsB[0][0];
    const int t8 = tid * 8;

#define STG_A(buf, half, kt) do {                                         \
        const unsigned short* g_ = pA + (size_t)((half) * 128) * DIM + (kt) * BK; \
        gload16(g_,            lA + (buf) * 16384 + (half) * 8192 + t8);        \
        gload16(g_ + 64 * DIM, lA + (buf) * 16384 + (half) * 8192 + 4096 + t8); \
    } while (0)
#define STG_B(buf, half, kt) do {                                         \
        const unsigned short* g_ = pB + (size_t)((half) * 128) * DIM + (kt) * BK; \
        gload16(g_,            lB + (buf) * 16384 + (half) * 8192 + t8);        \
        gload16(g_ + 64 * DIM, lB + (buf) * 16384 + (half) * 8192 + 4096 + t8); \
    } while (0)
// swizzled reads: phys slot = logical slot XOR (row&7); row&7 == fr&7 here
#define DS_A(buf, m, s) (*(const s16x8*)(lA + (buf) * 16384 + \
        (wr * 128 + (m) * 16 + fr) * BK + ((((s) * 4 + fg) ^ (fr & 7)) << 3)))
#define DS_B(buf, n, s) (*(const s16x8*)(lB + (buf) * 16384 + \
        (wc * 64 + (n) * 16 + fr) * BK + ((((s) * 4 + fg) ^ (fr & 7)) << 3)))

    f32x4 acc[8][4];
#pragma unroll
    for (int m = 0; m < 8; ++m)
#pragma unroll
        for (int n = 0; n < 4; ++n) acc[m][n] = (f32x4){0.f, 0.f, 0.f, 0.f};

    // prologue: t0.A0, t0.B0, t0.B1, t0.A1, t1.A0  (issue order matters)
    STG_A(0, 0, 0);
    STG_B(0, 0, 0);
    STG_B(0, 1, 0);
    STG_A(0, 1, 0);
    STG_A(1, 0, 1);
    asm volatile("s_waitcnt vmcnt(2)" ::: "memory");
    SBAR();

    s16x8 a[4][2], b[4][2];

    for (int C = 0; C < NKT; ++C) {
        const int cb = C & 1, nb = cb ^ 1;

        // ---- phase 0: mh=0, nh=0 ; reads A(mh0) x8 + B(n0,n1) x4 ; stage (C+1).B0
#pragma unroll
        for (int i = 0; i < 4; ++i)
#pragma unroll
            for (int s = 0; s < 2; ++s) a[i][s] = DS_A(cb, i, s);
#pragma unroll
        for (int j = 0; j < 2; ++j)
#pragma unroll
            for (int s = 0; s < 2; ++s) b[j][s] = DS_B(cb, j, s);
        if (C < NKT - 1) STG_B(nb, 0, C + 1);
        SBAR();
        __builtin_amdgcn_s_setprio(1);
#pragma unroll
        for (int s = 0; s < 2; ++s)
#pragma unroll
            for (int i = 0; i < 4; ++i)
#pragma unroll
                for (int j = 0; j < 2; ++j)
                    acc[i][j] = __builtin_amdgcn_mfma_f32_16x16x32_bf16(a[i][s], b[j][s], acc[i][j], 0, 0, 0);
        __builtin_amdgcn_s_setprio(0);
        SBAR();

        // ---- phase 1: mh=0, nh=1 ; reads B(n2,n3) x4 ; stage (C+1).B1 ; vmcnt
#pragma unroll
        for (int j = 2; j < 4; ++j)
#pragma unroll
            for (int s = 0; s < 2; ++s) b[j][s] = DS_B(cb, j, s);
        if (C < NKT - 1) {
            STG_B(nb, 1, C + 1);
            asm volatile("s_waitcnt vmcnt(6)" ::: "memory");
        } else {
            asm volatile("s_waitcnt vmcnt(0)" ::: "memory");
        }
        SBAR();
        __builtin_amdgcn_s_setprio(1);
#pragma unroll
        for (int s = 0; s < 2; ++s)
#pragma unroll
            for (int i = 0; i < 4; ++i)
#pragma unroll
                for (int j = 0; j < 2; ++j)
                    acc[i][2 + j] = __builtin_amdgcn_mfma_f32_16x16x32_bf16(a[i][s], b[2 + j][s], acc[i][2 + j], 0, 0, 0);
        __builtin_amdgcn_s_setprio(0);
        SBAR();

        // ---- phase 2: mh=1, nh=0 ; reads A(mh1) x8 ; stage (C+1).A1
#pragma unroll
        for (int i = 0; i < 4; ++i)
#pragma unroll
            for (int s = 0; s < 2; ++s) a[i][s] = DS_A(cb, 4 + i, s);
        if (C < NKT - 1) STG_A(nb, 1, C + 1);
        SBAR();
        __builtin_amdgcn_s_setprio(1);
#pragma unroll
        for (int s = 0; s < 2; ++s)
#pragma unroll
            for (int i = 0; i < 4; ++i)
#pragma unroll
                for (int j = 0; j < 2; ++j)
                    acc[4 + i][j] = __builtin_amdgcn_mfma_f32_16x16x32_bf16(a[i][s], b[j][s], acc[4 + i][j], 0, 0, 0);
        __builtin_amdgcn_s_setprio(0);
        SBAR();

        // ---- phase 3: mh=1, nh=1 ; no reads ; stage (C+2).A0 ; vmcnt
        if (C < NKT - 2) {
            STG_A(cb, 0, C + 2);
            asm volatile("s_waitcnt vmcnt(4)" ::: "memory");
        } else if (C == NKT - 2) {
            asm volatile("s_waitcnt vmcnt(2)" ::: "memory");
        }
        SBAR();
        __builtin_amdgcn_s_setprio(1);
#pragma unroll
        for (int s = 0; s < 2; ++s)
#pragma unroll
            for (int i = 0; i < 4; ++i)
#pragma unroll
                for (int j = 0; j < 2; ++j)
                    acc[4 + i][2 + j] = __builtin_amdgcn_mfma_f32_16x16x32_bf16(a[i][s], b[2 + j][s], acc[4 + i][2 + j], 0, 0, 0);
        __builtin_amdgcn_s_setprio(0);
        SBAR();
    }

    // epilogue: d2 = |a|^2+|b|^2-2ab, exp-sum
    float rn[8][4];
#pragma unroll
    for (int m = 0; m < 8; ++m)
#pragma unroll
        for (int v = 0; v < 4; ++v)
            rn[m][v] = zn[rA + wr * 128 + m * 16 + fg * 4 + v];
    float cn[4];
#pragma unroll
    for (int n = 0; n < 4; ++n) cn[n] = zn[rB + wc * 64 + n * 16 + fr];

    float lsum = 0.0f;
#pragma unroll
    for (int m = 0; m < 8; ++m)
#pragma unroll
        for (int n = 0; n < 4; ++n)
#pragma unroll
            for (int v = 0; v < 4; ++v) {
                float d2 = fmaf(-2.0f, acc[m][n][v], rn[m][v] + cn[n]);
                lsum += __expf(-d2 * INV_SIGMA);
            }

    double d = (double)lsum;
#pragma unroll
    for (int o = 32; o > 0; o >>= 1) d += __shfl_down(d, o);
    if (l == 0) red[wid] = d;
    __syncthreads();
    if (tid == 0) {
        double t = 0.0;
#pragma unroll
        for (int i = 0; i < 8; ++i) t += red[i];
        partials[blockIdx.x] = t * (double)factor;
    }
#undef STG_A
#undef STG_B
#undef DS_A
#undef DS_B
}

__global__ __launch_bounds__(256) void mmd_reduce(const double* __restrict__ partials,
                                                  float* __restrict__ out, int n) {
    __shared__ double red[256];
    double s = 0.0;
    for (int i = threadIdx.x; i < n; i += 256) s += partials[i];
    red[threadIdx.x] = s;
    __syncthreads();
    for (int ofs = 128; ofs > 0; ofs >>= 1) {
        if (threadIdx.x < ofs) red[threadIdx.x] += red[threadIdx.x + ofs];
        __syncthreads();
    }
    if (threadIdx.x == 0)
        out[0] = (float)(red[0] / ((double)N_ROWS * (double)N_ROWS));
}

// ---- fallback fp32 path (R1, proven) ----
__global__ __launch_bounds__(256) void mmd_norms_f32(const float* __restrict__ x,
                                                     const float* __restrict__ y,
                                                     float* __restrict__ zn) {
    int row = blockIdx.x * 4 + (threadIdx.x >> 6);
    int lane = threadIdx.x & 63;
    const float* p = (row < N_ROWS) ? (x + (size_t)row * DIM)
                                    : (y + (size_t)(row - N_ROWS) * DIM);
    float s = 0.0f;
#pragma unroll
    for (int c = 0; c < 4; ++c) {
        float4 v = *(const float4*)(p + (size_t)(lane + c * 64) * 4);
        s = fmaf(v.x, v.x, s);
        s = fmaf(v.y, v.y, s);
        s = fmaf(v.z, v.z, s);
        s = fmaf(v.w, v.w, s);
    }
#pragma unroll
    for (int o = 32; o > 0; o >>= 1) s += __shfl_down(s, o);
    if (lane == 0) zn[row] = s;
}

__global__ __launch_bounds__(256) void mmd_main_f32(const float* __restrict__ x,
                                                    const float* __restrict__ y,
                                                    const float* __restrict__ zn,
                                                    double* __restrict__ partials) {
    int bid = blockIdx.x;
    int tj = (int)((sqrtf(8.0f * (float)bid + 1.0f) - 1.0f) * 0.5f);
    while ((tj + 1) * (tj + 2) / 2 <= bid) ++tj;
    while (tj * (tj + 1) / 2 > bid) --tj;
    int ti = bid - tj * (tj + 1) / 2;

    const float* A = (ti < 64) ? (x + (size_t)ti * 128 * DIM)
                               : (y + (size_t)(ti - 64) * 128 * DIM);
    const float* B = (tj < 64) ? (x + (size_t)tj * 128 * DIM)
                               : (y + (size_t)(tj - 64) * 128 * DIM);
    float w = ((ti < 64) == (tj < 64)) ? 1.0f : -1.0f;
    float factor = (ti == tj) ? w : 2.0f * w;

    __shared__ float fsa[32][128];
    __shared__ float fsb[32][128];
    __shared__ double red[256];

    int tid = threadIdx.x;
    int tx = tid & 15;
    int ty = tid >> 4;

    float acc[8][8];
#pragma unroll
    for (int r = 0; r < 8; ++r)
#pragma unroll
        for (int s = 0; s < 8; ++s) acc[r][s] = 0.0f;

    for (int k0 = 0; k0 < DIM; k0 += 32) {
#pragma unroll
        for (int u = 0; u < 4; ++u) {
            int f = tid + u * 256;
            int row = f >> 3;
            int kk = (f & 7) << 2;
            float4 va = *(const float4*)(A + (size_t)row * DIM + k0 + kk);
            float4 vb = *(const float4*)(B + (size_t)row * DIM + k0 + kk);
            fsa[kk + 0][row] = va.x; fsa[kk + 1][row] = va.y;
            fsa[kk + 2][row] = va.z; fsa[kk + 3][row] = va.w;
            fsb[kk + 0][row] = vb.x; fsb[kk + 1][row] = vb.y;
            fsb[kk + 2][row] = vb.z; fsb[kk + 3][row] = vb.w;
        }
        __syncthreads();
#pragma unroll 8
        for (int k = 0; k < 32; ++k) {
            float4 a0 = *(const float4*)&fsa[k][ty * 8];
            float4 a1 = *(const float4*)&fsa[k][ty * 8 + 4];
            float4 b0 = *(const float4*)&fsb[k][tx * 8];
            float4 b1 = *(const float4*)&fsb[k][tx * 8 + 4];
            float af[8] = {a0.x, a0.y, a0.z, a0.w, a1.x, a1.y, a1.z, a1.w};
            float bfv[8] = {b0.x, b0.y, b0.z, b0.w, b1.x, b1.y, b1.z, b1.w};
#pragma unroll
            for (int r = 0; r < 8; ++r)
#pragma unroll
                for (int s = 0; s < 8; ++s)
                    acc[r][s] = fmaf(af[r], bfv[s], acc[r][s]);
        }
        __syncthreads();
    }

    float xnrm[8], ynrm[8];
#pragma unroll
    for (int r = 0; r < 8; ++r) xnrm[r] = zn[ti * 128 + ty * 8 + r];
#pragma unroll
    for (int s = 0; s < 8; ++s) ynrm[s] = zn[tj * 128 + tx * 8 + s];

    float lsum = 0.0f;
#pragma unroll
    for (int r = 0; r < 8; ++r)
#pragma unroll
        for (int s = 0; s < 8; ++s) {
            float d2 = fmaf(-2.0f, acc[r][s], xnrm[r] + ynrm[s]);
            lsum += __expf(-d2 * INV_SIGMA);
        }

    red[tid] = (double)lsum;
    __syncthreads();
#pragma unroll
    for (int ofs = 128; ofs > 0; ofs >>= 1) {
        if (tid < ofs) red[tid] += red[tid + ofs];
        __syncthreads();
    }
    if (tid == 0) partials[bid] = red[0] * (double)factor;
}

extern "C" void kernel_launch(void* const* d_in, const int* in_sizes, int n_in,
                              void* d_out, int out_size, void* d_ws, size_t ws_size,
                              hipStream_t stream) {
    const float* x = (const float*)d_in[0];
    const float* y = (const float*)d_in[1];
    float* out = (float*)d_out;

    const size_t zh_bytes = (size_t)TWO_N * DIM * sizeof(unsigned short); // 32 MiB
    const size_t zn_bytes = (size_t)TWO_N * sizeof(float);
    const size_t pt_bytes = (size_t)NBLK2 * sizeof(double);
    const size_t need = zh_bytes + zn_bytes + pt_bytes;

    if (ws_size >= need) {
        unsigned short* zh = (unsigned short*)d_ws;
        float* zn = (float*)((char*)d_ws + zh_bytes);
        double* partials = (double*)((char*)d_ws + zh_bytes + zn_bytes);
        mmd_convert<<<TWO_N / 4, 256, 0, stream>>>(x, y, zh, zn);
        mmd_main8<<<NBLK2, 512, 0, stream>>>(zh, zn, partials);
        mmd_reduce<<<1, 256, 0, stream>>>(partials, out, NBLK2);
    } else {
        float* zn = (float*)d_ws;
        double* partials = (double*)((char*)d_ws + (size_t)TWO_N * sizeof(float));
        mmd_norms_f32<<<TWO_N / 4, 256, 0, stream>>>(x, y, zn);
        mmd_main_f32<<<128 * 129 / 2, 256, 0, stream>>>(x, y, zn, partials);
        mmd_reduce<<<1, 256, 0, stream>>>(partials, out, 128 * 129 / 2);
    }
}